// Round 8
// baseline (1254.686 us; speedup 1.0000x reference)
//
#include <hip/hip_runtime.h>
#include <hip/hip_bf16.h>

#define IN_F 128
#define HF 256
#define BN_EPS 1e-5f
#define SELU_SCALE 1.0507009873554805f
#define SELU_ALPHA 1.6732632423543772f

typedef __attribute__((ext_vector_type(8))) _Float16 half8;
typedef __attribute__((ext_vector_type(4))) _Float16 half4v;
typedef __attribute__((ext_vector_type(2))) float f32x2;
typedef __attribute__((ext_vector_type(4))) float f32x4;

__device__ __forceinline__ float selu_f(float x) {
    return SELU_SCALE * (x > 0.f ? x : SELU_ALPHA * expm1f(x));
}

// async global->LDS, 16B per lane; LDS dest = wave-uniform base + lane*16
__device__ __forceinline__ void gld_lds16(const void* g, void* l) {
    __builtin_amdgcn_global_load_lds(
        (const __attribute__((address_space(1))) unsigned int*)g,
        (__attribute__((address_space(3))) unsigned int*)l, 16, 0, 0);
}

// Fold BN into weights. Layout for the fused kernel's per-slice LDS staging:
// Wf[layer][slice(8)][g(4)][row(256)][j(8)] fp16, where k = slice*32 + g*8 + j.
// Each (layer,slice) chunk is 16KB contiguous; within it, a P-fragment read is
// lane: byte g*4096 + (16ci+e)*16 -> dense 16B/lane over contiguous memory
// (conflict-free ds_read_b128).
__global__ void prep_kernel(const float* __restrict__ W0, const float* __restrict__ b0,
                            const float* __restrict__ g0, const float* __restrict__ beta0,
                            const float* __restrict__ m0, const float* __restrict__ v0,
                            const float* __restrict__ Ws, const float* __restrict__ bs,
                            const float* __restrict__ gs, const float* __restrict__ betas,
                            const float* __restrict__ ms, const float* __restrict__ vs,
                            unsigned short* __restrict__ Wf, float* __restrict__ biasArr) {
    int b = blockIdx.x;
    int layer = b >> 8;
    int n = b & 255;
    int k = threadIdx.x;
    const float *W, *bb, *g, *be, *m, *v;
    if (layer == 0) { W = W0; bb = b0; g = g0; be = beta0; m = m0; v = v0; }
    else {
        int i = layer - 1;
        W = Ws + (size_t)i * HF * HF; bb = bs + i * HF; g = gs + i * HF;
        be = betas + i * HF; m = ms + i * HF; v = vs + i * HF;
    }
    float s = g[n] * rsqrtf(v[n] + BN_EPS);
    _Float16 hv = (_Float16)(W[n * HF + k] * s);
    int slice = k >> 5, grp = (k >> 3) & 3, j = k & 7;
    Wf[((((size_t)layer * 8 + slice) * 4 + grp) * 256 + n) * 8 + j] =
        __builtin_bit_cast(unsigned short, hv);
    if (k == 0) biasArr[layer * HF + n] = (bb[n] - m[n]) * s + be[n];
}

__global__ void count_kernel(const int* __restrict__ dstI, int* __restrict__ cnt, int E) {
    int i = blockIdx.x * 256 + threadIdx.x;
    if (i < E) atomicAdd(cnt + dstI[i], 1);
}

__global__ void finalize_kernel(float* __restrict__ agg, const int* __restrict__ cnt) {
    int n = blockIdx.x;
    float c = fmaxf((float)cnt[n], 1.f);
    agg[(size_t)n * HF + threadIdx.x] = agg[(size_t)n * HF + threadIdx.x] / c;
}

// Fused 3-layer edge-MLP. Block = 64 edges, 256 thr = 4 waves; each wave owns
// 16 edges x ALL 256 cols. Every layer: mfma(P=W_frag, Q=h_frag) so that
// D[p=outcol][q=edge] keeps lane&15 = edge -- the activation never leaves the
// wave. acc = 16 x f32x4; next-layer Q operand (32 VGPR) is rebuilt from acc
// via a wave-private 8KB LDS bounce (no barrier): lane(e,g) holds cols
// {16ci+4g+r}; pack 4 fp16 -> write b64 at k-bytes 32ci+8g (XOR-swizzled);
// read back q[s] = 16B at k-bytes 64s+16g. W staged per 32-k slice (16KB,
// double-buffered in the same 32KB LDS used by the bounce & epilogue).
// Epilogue: fp32 atomics into agg from acc + LDS-transposed full-line h rows.
__global__ __launch_bounds__(256)
void fused_kernel(const float* __restrict__ x,
                  const int* __restrict__ dstI, const int* __restrict__ srcI,
                  const unsigned short* __restrict__ Wf,
                  const float* __restrict__ biasArr,
                  float* __restrict__ h, float* __restrict__ agg) {
    __shared__ __align__(16) unsigned char lds[32768];

    const int t = threadIdx.x;
    const int lane = t & 63;
    const int w = t >> 6;           // 0..3
    const int e = lane & 15;        // edge within wave
    const int g = lane >> 4;        // k-group
    const int edge = blockIdx.x * 64 + w * 16 + e;
    const int di = dstI[edge];
    const int si = srcI[edge];

    // ---- layer-1 Q operand: gather x (fp32, L2/L3-hot) -> fp16 in regs ----
    // k = 32s + 8g + j ; s<4 -> x[dst], s>=4 -> x[src] (concat at k=128)
    half8 q[8];
#pragma unroll
    for (int s = 0; s < 8; ++s) {
        const float* src = x + (size_t)((s < 4) ? di : si) * IN_F + (s & 3) * 32 + g * 8;
        f32x4 v0 = *(const f32x4*)src;
        f32x4 v1 = *(const f32x4*)(src + 4);
        half8 qq;
        qq[0] = (_Float16)v0[0]; qq[1] = (_Float16)v0[1];
        qq[2] = (_Float16)v0[2]; qq[3] = (_Float16)v0[3];
        qq[4] = (_Float16)v1[0]; qq[5] = (_Float16)v1[1];
        qq[6] = (_Float16)v1[2]; qq[7] = (_Float16)v1[3];
        q[s] = qq;
    }

    f32x4 acc[16];

#pragma unroll
    for (int L = 0; L < 3; ++L) {
        // stage W slices 0,1 of this layer (16KB each; 4 x gld_lds per wave)
#pragma unroll
        for (int sp = 0; sp < 2; ++sp) {
            const unsigned char* gsrc = (const unsigned char*)Wf
                + ((size_t)(L * 8 + sp) << 14) + lane * 16;
            unsigned char* dst = lds + sp * 16384;
#pragma unroll
            for (int i = 0; i < 4; ++i) {
                int c = w * 4 + i;
                gld_lds16(gsrc + c * 1024, dst + c * 1024);
            }
        }
        const f32x4 zero = {0.f, 0.f, 0.f, 0.f};
#pragma unroll
        for (int ci = 0; ci < 16; ++ci) acc[ci] = zero;
        __syncthreads();

#pragma unroll
        for (int s = 0; s < 8; ++s) {
            const unsigned char* cur = lds + (s & 1) * 16384 + g * 4096;
            if (s >= 1 && s < 7) {      // stage slice s+1 into the other buffer
                const unsigned char* gsrc = (const unsigned char*)Wf
                    + ((size_t)(L * 8 + s + 1) << 14) + lane * 16;
                unsigned char* dst = lds + ((s + 1) & 1) * 16384;
#pragma unroll
                for (int i = 0; i < 4; ++i) {
                    int c = w * 4 + i;
                    gld_lds16(gsrc + c * 1024, dst + c * 1024);
                }
            }
#pragma unroll
            for (int ci = 0; ci < 16; ++ci) {
                half8 p = *(const half8*)&cur[(ci * 16 + e) * 16];
                acc[ci] = __builtin_amdgcn_mfma_f32_16x16x32_f16(p, q[s], acc[ci], 0, 0, 0);
            }
            __syncthreads();
        }

        // ---- bias + SELU (col of acc[ci][r] = 16ci + 4g + r) ----
#pragma unroll
        for (int ci = 0; ci < 16; ++ci) {
            f32x4 bv = *(const f32x4*)(biasArr + L * HF + ci * 16 + g * 4);
#pragma unroll
            for (int r = 0; r < 4; ++r) acc[ci][r] = selu_f(acc[ci][r] + bv[r]);
        }

        if (L < 2) {
            // ---- wave-private LDS bounce: acc -> next-layer Q operand ----
            unsigned char* slot = lds + w * 8192;
            const int swz = (e & 7) << 4;
#pragma unroll
            for (int ci = 0; ci < 16; ++ci) {
                half4v hv = {(_Float16)acc[ci][0], (_Float16)acc[ci][1],
                             (_Float16)acc[ci][2], (_Float16)acc[ci][3]};
                *(half4v*)&slot[e * 512 + ((ci * 32 + g * 8) ^ swz)] = hv;
            }
#pragma unroll
            for (int s = 0; s < 8; ++s)
                q[s] = *(const half8*)&slot[e * 512 + ((s * 64 + g * 16) ^ swz)];
            __syncthreads();   // all waves done with bounce before W restage
        }
    }

    // ---- epilogue: atomic scatter into agg + full-line h rows via LDS ----
    {
        float* ap = agg + (size_t)di * HF;
#pragma unroll
        for (int ci = 0; ci < 16; ++ci) {
            int c0 = ci * 16 + g * 4;
            atomicAdd(ap + c0 + 0, acc[ci][0]);
            atomicAdd(ap + c0 + 1, acc[ci][1]);
            atomicAdd(ap + c0 + 2, acc[ci][2]);
            atomicAdd(ap + c0 + 3, acc[ci][3]);
        }
        unsigned char* hB = (unsigned char*)h + ((size_t)blockIdx.x << 16);  // 64 rows x 1KB
#pragma unroll
        for (int p = 0; p < 2; ++p) {
            if (p) __syncthreads();
            if ((w >> 1) == p) {            // waves 2p,2p+1 own rows 32p..32p+31
                int rl = (w & 1) * 16 + e;
                int sz = (rl & 7) << 4;
#pragma unroll
                for (int ci = 0; ci < 16; ++ci) {
                    int cb = ci * 64 + g * 16;
                    f32x2 a01 = {acc[ci][0], acc[ci][1]};
                    f32x2 a23 = {acc[ci][2], acc[ci][3]};
                    *(f32x2*)&lds[rl * 1024 + (cb ^ sz)] = a01;
                    *(f32x2*)&lds[rl * 1024 + ((cb + 8) ^ sz)] = a23;
                }
            }
            __syncthreads();
#pragma unroll
            for (int i = 0; i < 8; ++i) {
                int f = t + i * 256;                  // 2048 x 16B = 32 rows x 64
                int row = f >> 6, ch = f & 63;
                f32x4 v = *(const f32x4*)&lds[row * 1024 + ((ch * 16) ^ ((row & 7) << 4))];
                *(f32x4*)&hB[(size_t)(p * 32 + row) * 1024 + ch * 16] = v;
            }
        }
    }
}

extern "C" void kernel_launch(void* const* d_in, const int* in_sizes, int n_in,
                              void* d_out, int out_size, void* d_ws, size_t ws_size,
                              hipStream_t stream) {
    const float* x     = (const float*)d_in[0];
    const int*   ei    = (const int*)d_in[1];
    const float* W0    = (const float*)d_in[2];
    const float* b0    = (const float*)d_in[3];
    const float* g0    = (const float*)d_in[4];
    const float* beta0 = (const float*)d_in[5];
    const float* m0    = (const float*)d_in[6];
    const float* v0    = (const float*)d_in[7];
    const float* Ws    = (const float*)d_in[8];
    const float* bs    = (const float*)d_in[9];
    const float* gs    = (const float*)d_in[10];
    const float* betas = (const float*)d_in[11];
    const float* ms    = (const float*)d_in[12];
    const float* vs    = (const float*)d_in[13];

    const int Nn = in_sizes[0] / IN_F;   // 20000
    const int E  = in_sizes[1] / 2;      // 320000

    float* agg  = (float*)d_out;
    float* hptr = agg + (size_t)Nn * HF;   // final h region of d_out

    // ws: Wf (384KB fused-layout fp16) | biasArr (3KB) | cnt (80KB)
    unsigned short* Wf = (unsigned short*)d_ws;
    float* biasArr = (float*)((char*)d_ws + 3 * HF * HF * sizeof(unsigned short));
    int* cnt = (int*)((char*)d_ws + 3 * HF * HF * sizeof(unsigned short) + 3 * HF * sizeof(float));

    const int* srcI = ei;        // edge_index[0]
    const int* dstI = ei + E;    // edge_index[1]

    prep_kernel<<<3 * HF, HF, 0, stream>>>(W0, b0, g0, beta0, m0, v0,
                                           Ws, bs, gs, betas, ms, vs, Wf, biasArr);
    hipMemsetAsync(cnt, 0, (size_t)Nn * sizeof(int), stream);
    count_kernel<<<(E + 255) / 256, 256, 0, stream>>>(dstI, cnt, E);
    hipMemsetAsync(agg, 0, (size_t)Nn * HF * sizeof(float), stream);

    fused_kernel<<<E / 64, 256, 0, stream>>>(x, dstI, srcI, Wf, biasArr, hptr, agg);

    finalize_kernel<<<Nn, HF, 0, stream>>>(agg, cnt);
}

// Round 9
// 727.374 us; speedup vs baseline: 1.7250x; 1.7250x over previous
//
#include <hip/hip_runtime.h>
#include <hip/hip_bf16.h>

#define IN_F 128
#define HF 256
#define BN_EPS 1e-5f
#define SELU_SCALE 1.0507009873554805f
#define SELU_ALPHA 1.6732632423543772f

typedef __attribute__((ext_vector_type(8))) _Float16 half8;
typedef __attribute__((ext_vector_type(4))) short short4v;
typedef __attribute__((ext_vector_type(4))) float f32x4;

__device__ __forceinline__ short f2h(float f) {
    _Float16 h = (_Float16)f;               // RTNE fp32->fp16
    return __builtin_bit_cast(short, h);
}

__device__ __forceinline__ float selu_f(float x) {
    return SELU_SCALE * (x > 0.f ? x : SELU_ALPHA * expm1f(x));
}

// async global->LDS, 16B per lane; LDS dest = wave-uniform base + lane*16
__device__ __forceinline__ void gld_lds16(const void* g, void* l) {
    __builtin_amdgcn_global_load_lds(
        (const __attribute__((address_space(1))) unsigned int*)g,
        (__attribute__((address_space(3))) unsigned int*)l, 16, 0, 0);
}

// x fp32 -> fp16 (plain layout), parked in the agg region of d_out (dead until GEMM1 done)
__global__ void cvt_x_kernel(const float* __restrict__ x, unsigned short* __restrict__ x16, int n4) {
    int i = blockIdx.x * 256 + threadIdx.x;
    if (i < n4) {
        f32x4 v = ((const f32x4*)x)[i];
        short4v p;
        p[0] = f2h(v[0]); p[1] = f2h(v[1]); p[2] = f2h(v[2]); p[3] = f2h(v[3]);
        ((short4v*)x16)[i] = p;
    }
}

// Fold BN into weights; store fp16 PLAIN row-major [n][k].
__global__ void prep_kernel(const float* __restrict__ W0, const float* __restrict__ b0,
                            const float* __restrict__ g0, const float* __restrict__ beta0,
                            const float* __restrict__ m0, const float* __restrict__ v0,
                            const float* __restrict__ Ws, const float* __restrict__ bs,
                            const float* __restrict__ gs, const float* __restrict__ betas,
                            const float* __restrict__ ms, const float* __restrict__ vs,
                            unsigned short* __restrict__ Wh, float* __restrict__ biasArr) {
    int b = blockIdx.x;
    int layer = b >> 8;
    int n = b & 255;
    int k = threadIdx.x;
    const float *W, *bb, *g, *be, *m, *v;
    if (layer == 0) { W = W0; bb = b0; g = g0; be = beta0; m = m0; v = v0; }
    else {
        int i = layer - 1;
        W = Ws + (size_t)i * HF * HF; bb = bs + i * HF; g = gs + i * HF;
        be = betas + i * HF; m = ms + i * HF; v = vs + i * HF;
    }
    float s = g[n] * rsqrtf(v[n] + BN_EPS);
    Wh[(size_t)layer * HF * HF + n * HF + k] = (unsigned short)f2h(W[n * HF + k] * s);
    if (k == 0) biasArr[layer * HF + n] = (bb[n] - m[n]) * s + be[n];
}

__global__ void count_kernel(const int* __restrict__ dstI, int* __restrict__ cnt, int E) {
    int i = blockIdx.x * 256 + threadIdx.x;
    if (i < E) atomicAdd(cnt + dstI[i], 1);
}

__global__ void finalize_kernel(float* __restrict__ agg, const int* __restrict__ cnt) {
    int n = blockIdx.x;
    float c = fmaxf((float)cnt[n], 1.f);
    agg[(size_t)n * HF + threadIdx.x] = agg[(size_t)n * HF + threadIdx.x] / c;
}

// One block = 128 edges x all 256 cols. 512 thr = 8 waves (2 row-halves x 4 col
// slabs); wave tile 64x64 via 4x4 frags of mfma_f32_16x16x32_f16.
// BK=32, 8 k-steps, STAGE-AHEAD double buffering: loads for step k+1 issued
// before step k's ds_reads/MFMA; one barrier per step. LDS 48KB:
//   A dbuf 2x8KB @0, B dbuf 2x16KB @16384. Epilogue reuses [0,32768).
// Slice layout [sub(4)][row][16B]: frag ds_read = 16 lanes x contiguous 256B,
// conflict-free, no LDS swizzle. hh rows stay swizzled (epilogue needs it);
// the stage's GLOBAL source address XORs it away (pre-swizzled-source pattern).
// MODE 0: A = gather-concat x16 -> hh fp16 ; MODE 1: hh -> hh (in-place)
// MODE 2: hh -> final h fp32 full rows + atomic scatter into agg
template <int MODE>
__global__ __launch_bounds__(512)
void gemm_kernel(const unsigned short* __restrict__ x16,
                 const unsigned char* __restrict__ hhB,
                 const int* __restrict__ dstI, const int* __restrict__ srcI,
                 const unsigned short* __restrict__ Wh,   // this layer, plain [n][k]
                 const float* __restrict__ biasArr,       // this layer
                 unsigned char* __restrict__ outB,
                 float* __restrict__ agg) {
    __shared__ __align__(16) unsigned char lds[49152];

    const int base = blockIdx.x * 128;
    const int t = threadIdx.x;
    const int lane = t & 63;
    const int w = t >> 6;           // 0..7
    const int wr = w >> 2;          // 0..1 : 64-row half
    const int wcol = w & 3;         // 0..3 : 64-col slab
    const int lrow = lane & 15;
    const int lgrp = lane >> 4;

    // staging roles (step-invariant)
    const int arow = (w & 1) * 64 + lane;   // A tile row this thread stages
    const int asub = w >> 1;                // A 16B sub-chunk 0..3
    const int bn0 = (w & 3) * 64 + lane;    // B weight row for blk w / w+8
    const int bsub0 = w >> 2;               // 0..1
    const int bsub1 = bsub0 + 2;            // 2..3

    int aid = 0, ais = 0;
    if (MODE == 0) { aid = dstI[base + arow]; ais = srcI[base + arow]; }

    auto stage = [&](int kk, int buf) {
        unsigned char* Ab = lds + buf * 8192;
        unsigned char* Bb = lds + 16384 + buf * 16384;
        const unsigned char* ga;
        if (MODE == 0) {
            int idx = (kk < 4) ? aid : ais;
            ga = (const unsigned char*)x16 + (size_t)idx * 256 + (kk & 3) * 64 + asub * 16;
        } else {
            ga = hhB + (size_t)(base + arow) * 1024 + (kk >> 1) * 128
                 + (((kk & 1) * 64 + asub * 16) ^ ((arow & 7) << 4));
        }
        gld_lds16(ga, Ab + w * 1024);
        const unsigned char* gb = (const unsigned char*)Wh + (size_t)bn0 * 512 + kk * 64;
        gld_lds16(gb + bsub0 * 16, Bb + w * 1024);
        gld_lds16(gb + bsub1 * 16, Bb + 8192 + w * 1024);
    };

    // prologue
    stage(0, 0);
    __syncthreads();

    f32x4 acc[4][4];
    const f32x4 zero = {0.f, 0.f, 0.f, 0.f};
#pragma unroll
    for (int mi = 0; mi < 4; ++mi)
#pragma unroll
        for (int ni = 0; ni < 4; ++ni) acc[mi][ni] = zero;

#pragma unroll
    for (int kk = 0; kk < 8; ++kk) {
        const int cur = kk & 1;
        if (kk < 7) stage(kk + 1, cur ^ 1);   // issue next-step loads FIRST

        const unsigned char* Ab = lds + cur * 8192;
        const unsigned char* Bb = lds + 16384 + cur * 16384;
        half8 af[4], bf[4];
#pragma unroll
        for (int mi = 0; mi < 4; ++mi)
            af[mi] = *(const half8*)&Ab[lgrp * 2048 + (wr * 64 + mi * 16 + lrow) * 16];
#pragma unroll
        for (int ni = 0; ni < 4; ++ni)
            bf[ni] = *(const half8*)&Bb[lgrp * 4096 + (wcol * 64 + ni * 16 + lrow) * 16];
#pragma unroll
        for (int mi = 0; mi < 4; ++mi)
#pragma unroll
            for (int ni = 0; ni < 4; ++ni)
                acc[mi][ni] = __builtin_amdgcn_mfma_f32_16x16x32_f16(
                    af[mi], bf[ni], acc[mi][ni], 0, 0, 0);
        __syncthreads();   // reads of cur done; loads for cur^1 drained
    }

    float bc[4];
#pragma unroll
    for (int ni = 0; ni < 4; ++ni) bc[ni] = biasArr[wcol * 64 + ni * 16 + lrow];

    if (MODE < 2) {
        // fp16 swizzled out: 2 rounds of 64 rows (32KB stage)
#pragma unroll
        for (int cc = 0; cc < 2; ++cc) {
            if (cc) __syncthreads();
            if (wr == cc) {
#pragma unroll
                for (int mi = 0; mi < 4; ++mi)
#pragma unroll
                    for (int ni = 0; ni < 4; ++ni)
#pragma unroll
                        for (int r = 0; r < 4; ++r) {
                            int lr = mi * 16 + lgrp * 4 + r;          // 0..63
                            int cg = wcol * 64 + ni * 16 + lrow;      // 0..255
                            float val = selu_f(acc[mi][ni][r] + bc[ni]);
                            int pos = (cg >> 6) * 128 + (((cg & 63) * 2) ^ ((lr & 7) << 4));
                            *(short*)&lds[lr * 512 + pos] = f2h(val);
                        }
            }
            __syncthreads();
#pragma unroll
            for (int i = 0; i < 4; ++i) {
                int f = t + i * 512;                  // 2048 x 16B = 64 rows x 32
                int row = f >> 5, ch = f & 31;
                int e = base + cc * 64 + row;
                f32x4 v = *(const f32x4*)&lds[row * 512 + ch * 16];
                *(f32x4*)(outB + (size_t)e * 1024 + ch * 16) = v;
            }
        }
    } else {
        // fp32 plain out: 4 rounds of 32 rows (32KB stage) + atomic scatter
#pragma unroll
        for (int cc = 0; cc < 4; ++cc) {
            if (cc) __syncthreads();
            if (wr == (cc >> 1)) {
#pragma unroll
                for (int m2 = 0; m2 < 2; ++m2) {
                    int mi = (cc & 1) * 2 + m2;
#pragma unroll
                    for (int ni = 0; ni < 4; ++ni)
#pragma unroll
                        for (int r = 0; r < 4; ++r) {
                            int lr = m2 * 16 + lgrp * 4 + r;          // 0..31
                            int cg = wcol * 64 + ni * 16 + lrow;
                            float val = selu_f(acc[mi][ni][r] + bc[ni]);
                            *(float*)&lds[lr * 1024 + cg * 4] = val;
                            int e = base + cc * 32 + lr;
                            atomicAdd(agg + (size_t)dstI[e] * HF + cg, val);
                        }
                }
            }
            __syncthreads();
#pragma unroll
            for (int i = 0; i < 4; ++i) {
                int f = t + i * 512;                  // 2048 x 16B = 32 rows x 64
                int row = f >> 6, ch = f & 63;
                int e = base + cc * 32 + row;
                f32x4 v = *(const f32x4*)&lds[row * 1024 + ch * 16];
                *(f32x4*)(outB + (size_t)e * 1024 + ch * 16) = v;
            }
        }
    }
}

extern "C" void kernel_launch(void* const* d_in, const int* in_sizes, int n_in,
                              void* d_out, int out_size, void* d_ws, size_t ws_size,
                              hipStream_t stream) {
    const float* x     = (const float*)d_in[0];
    const int*   ei    = (const int*)d_in[1];
    const float* W0    = (const float*)d_in[2];
    const float* b0    = (const float*)d_in[3];
    const float* g0    = (const float*)d_in[4];
    const float* beta0 = (const float*)d_in[5];
    const float* m0    = (const float*)d_in[6];
    const float* v0    = (const float*)d_in[7];
    const float* Ws    = (const float*)d_in[8];
    const float* bs    = (const float*)d_in[9];
    const float* gs    = (const float*)d_in[10];
    const float* betas = (const float*)d_in[11];
    const float* ms    = (const float*)d_in[12];
    const float* vs    = (const float*)d_in[13];

    const int Nn = in_sizes[0] / IN_F;   // 20000
    const int E  = in_sizes[1] / 2;      // 320000

    float* agg  = (float*)d_out;
    float* hptr = agg + (size_t)Nn * HF;             // h region: E slots of 1KB
    unsigned char* hhB = (unsigned char*)hptr;       // fp16 intermediates in low 512B of each slot

    // ws: Wh (384KB plain fp16) | biasArr (3KB) | cnt (80KB)
    unsigned short* Wh = (unsigned short*)d_ws;
    float* biasArr = (float*)((char*)d_ws + 3 * HF * HF * sizeof(unsigned short));
    int* cnt = (int*)((char*)d_ws + 3 * HF * HF * sizeof(unsigned short) + 3 * HF * sizeof(float));

    const int* srcI = ei;        // edge_index[0]
    const int* dstI = ei + E;    // edge_index[1]

    // x16 (10.24MB fp16) parked in the agg region (dead until after GEMM1)
    unsigned short* x16 = (unsigned short*)d_out;

    cvt_x_kernel<<<(Nn * IN_F / 4 + 255) / 256, 256, 0, stream>>>(x, x16, Nn * IN_F / 4);
    prep_kernel<<<3 * HF, HF, 0, stream>>>(W0, b0, g0, beta0, m0, v0,
                                           Ws, bs, gs, betas, ms, vs, Wh, biasArr);
    hipMemsetAsync(cnt, 0, (size_t)Nn * sizeof(int), stream);
    count_kernel<<<(E + 255) / 256, 256, 0, stream>>>(dstI, cnt, E);

    gemm_kernel<0><<<E / 128, 512, 0, stream>>>(x16, hhB, dstI, srcI,
                                                Wh, biasArr, hhB, nullptr);
    hipMemsetAsync(agg, 0, (size_t)Nn * HF * sizeof(float), stream);   // x16 dead now
    gemm_kernel<1><<<E / 128, 512, 0, stream>>>(x16, hhB, dstI, srcI,
                                                Wh + HF * HF, biasArr + HF, hhB, nullptr);
    gemm_kernel<2><<<E / 128, 512, 0, stream>>>(x16, hhB, dstI, srcI,
                                                Wh + 2 * HF * HF, biasArr + 2 * HF,
                                                (unsigned char*)hptr, agg);

    finalize_kernel<<<Nn, HF, 0, stream>>>(agg, cnt);
}

// Round 10
// 485.469 us; speedup vs baseline: 2.5845x; 1.4983x over previous
//
#include <hip/hip_runtime.h>
#include <hip/hip_bf16.h>

#define IN_F 128
#define HF 256
#define BN_EPS 1e-5f
#define SELU_SCALE 1.0507009873554805f
#define SELU_ALPHA 1.6732632423543772f

typedef __attribute__((ext_vector_type(8))) _Float16 half8;
typedef __attribute__((ext_vector_type(4))) _Float16 half4v;
typedef __attribute__((ext_vector_type(4))) float f32x4;

__device__ __forceinline__ short f2h(float f) {
    _Float16 h = (_Float16)f;               // RTNE fp32->fp16
    return __builtin_bit_cast(short, h);
}

__device__ __forceinline__ float selu_f(float x) {
    return SELU_SCALE * (x > 0.f ? x : SELU_ALPHA * expm1f(x));
}

// async global->LDS, 16B/lane; LDS dest MUST be wave-uniform (lane*16 implicit)
__device__ __forceinline__ void gld_lds16(const void* g, void* l) {
    __builtin_amdgcn_global_load_lds(
        (const __attribute__((address_space(1))) unsigned int*)g,
        (__attribute__((address_space(3))) unsigned int*)l, 16, 0, 0);
}

// Fold BN into weights. Layout matches fused kernel's per-step B staging:
// Wf[layer][kk(4)][kc(8)][n(256)][j(8)] fp16, k = kk*64 + kc*8 + j.
// Each (layer,kk) block is 32KB contiguous -> staged with 8 contiguous
// gld_lds16 rounds; B frag read = consecutive-n 16B chunks (conflict-free).
__global__ void prep_kernel(const float* __restrict__ W0, const float* __restrict__ b0,
                            const float* __restrict__ g0, const float* __restrict__ beta0,
                            const float* __restrict__ m0, const float* __restrict__ v0,
                            const float* __restrict__ Ws, const float* __restrict__ bs,
                            const float* __restrict__ gs, const float* __restrict__ betas,
                            const float* __restrict__ ms, const float* __restrict__ vs,
                            unsigned short* __restrict__ Wf, float* __restrict__ biasArr) {
    int b = blockIdx.x;
    int layer = b >> 8;
    int n = b & 255;
    int k = threadIdx.x;
    const float *W, *bb, *g, *be, *m, *v;
    if (layer == 0) { W = W0; bb = b0; g = g0; be = beta0; m = m0; v = v0; }
    else {
        int i = layer - 1;
        W = Ws + (size_t)i * HF * HF; bb = bs + i * HF; g = gs + i * HF;
        be = betas + i * HF; m = ms + i * HF; v = vs + i * HF;
    }
    float s = g[n] * rsqrtf(v[n] + BN_EPS);
    int kk = k >> 6, kc = (k >> 3) & 7, j = k & 7;
    Wf[((((size_t)layer * 4 + kk) * 8 + kc) * 256 + n) * 8 + j] =
        (unsigned short)f2h(W[n * HF + k] * s);
    if (k == 0) biasArr[layer * HF + n] = (bb[n] - m[n]) * s + be[n];
}

__global__ void count_kernel(const int* __restrict__ dstI, int* __restrict__ cnt, int E) {
    int i = blockIdx.x * 256 + threadIdx.x;
    if (i < E) atomicAdd(cnt + dstI[i], 1);
}

__global__ void finalize_kernel(float* __restrict__ agg, const int* __restrict__ cnt) {
    int n = blockIdx.x;
    float c = fmaxf((float)cnt[n], 1.f);
    agg[(size_t)n * HF + threadIdx.x] = agg[(size_t)n * HF + threadIdx.x] / c;
}

// Fused 3-layer edge MLP. Block = 64 edges x all 256 cols; 256 thr = 4 waves,
// each wave 64 rows x 64 cols (4x4 frags of mfma_f32_16x16x32_f16).
// A_act: 64 rows x 512B fp16 in LDS @0, XOR-swizzled (byte ^ ((row&7)<<4)),
//   resident across layers: filled by gather (layer1), rewritten by handoffs.
// B: 32KB @32768, layout [kc][n][16B], staged per BK=64 step via gld_lds
//   (stage -> barrier -> compute -> barrier, R4's proven step). Epilogue
//   reuses the B region for full-line h stores + 64B-contiguous atomics.
__global__ __launch_bounds__(256, 2)
void fused_kernel(const float* __restrict__ x,
                  const int* __restrict__ dstI, const int* __restrict__ srcI,
                  const unsigned char* __restrict__ Wfb,
                  const float* __restrict__ biasArr,
                  unsigned char* __restrict__ hB, float* __restrict__ agg) {
    __shared__ __align__(16) unsigned char lds[65536];

    const int base = blockIdx.x * 64;
    const int t = threadIdx.x;
    const int lane = t & 63;
    const int w = t >> 6;           // 0..3 : 64-col slab
    const int lrow = lane & 15;
    const int lgrp = lane >> 4;

    // stage B(L,kk): 32KB, 8 wave-uniform gld_lds rounds
    auto stageB = [&](int L, int kk) {
        const unsigned char* src = Wfb + ((size_t)(L * 4 + kk) << 15);
        unsigned char* dstBase = lds + 32768 + w * 1024;
#pragma unroll
        for (int i = 0; i < 8; ++i)
            gld_lds16(src + (i * 256 + t) * 16, dstBase + i * 4096);
    };

    stageB(0, 0);   // overlap with gather below

    // ---- layer-1 A fill: gather x fp32 (L2/L3-hot), convert, swizzled write ----
    {
        int r = t >> 2, q = t & 3;                 // row, col-quarter
        int idx = (q < 2 ? dstI : srcI)[base + r];
        const float* xr = x + (size_t)idx * IN_F + (q & 1) * 64;
        int swz = (r & 7) << 4;
#pragma unroll
        for (int u = 0; u < 16; ++u) {
            f32x4 v = *(const f32x4*)(xr + u * 4);
            half4v hv = {(_Float16)v[0], (_Float16)v[1], (_Float16)v[2], (_Float16)v[3]};
            *(half4v*)&lds[r * 512 + ((q * 128 + u * 8) ^ swz)] = hv;
        }
    }

    f32x4 acc[4][4];
    const f32x4 zero = {0.f, 0.f, 0.f, 0.f};

#pragma unroll
    for (int L = 0; L < 3; ++L) {
        float bc[4];
#pragma unroll
        for (int ni = 0; ni < 4; ++ni) bc[ni] = biasArr[L * HF + w * 64 + ni * 16 + lrow];
#pragma unroll
        for (int mi = 0; mi < 4; ++mi)
#pragma unroll
            for (int ni = 0; ni < 4; ++ni) acc[mi][ni] = zero;

#pragma unroll
        for (int kk = 0; kk < 4; ++kk) {
            __syncthreads();   // B(kk) staged + A_act writes visible

            half8 af[4][2], bf[4][2];
#pragma unroll
            for (int mi = 0; mi < 4; ++mi)
#pragma unroll
                for (int kI = 0; kI < 2; ++kI) {
                    int row = mi * 16 + lrow;
                    af[mi][kI] = *(const half8*)&lds[row * 512 +
                        ((kk * 128 + kI * 64 + lgrp * 16) ^ ((row & 7) << 4))];
                }
#pragma unroll
            for (int ni = 0; ni < 4; ++ni)
#pragma unroll
                for (int kI = 0; kI < 2; ++kI)
                    bf[ni][kI] = *(const half8*)&lds[32768 + (kI * 4 + lgrp) * 4096 +
                                                     (w * 64 + ni * 16 + lrow) * 16];
#pragma unroll
            for (int kI = 0; kI < 2; ++kI)
#pragma unroll
                for (int mi = 0; mi < 4; ++mi)
#pragma unroll
                    for (int ni = 0; ni < 4; ++ni)
                        acc[mi][ni] = __builtin_amdgcn_mfma_f32_16x16x32_f16(
                            af[mi][kI], bf[ni][kI], acc[mi][ni], 0, 0, 0);
            __syncthreads();   // frag reads done -> B buffer / A_act free

            if (kk < 3) stageB(L, kk + 1);
            else if (L < 2) stageB(L + 1, 0);
        }

        if (L < 2) {
            // ---- handoff: SELU -> fp16 -> swizzled A_act rewrite ----
#pragma unroll
            for (int mi = 0; mi < 4; ++mi)
#pragma unroll
                for (int ni = 0; ni < 4; ++ni)
#pragma unroll
                    for (int r = 0; r < 4; ++r) {
                        int row = mi * 16 + lgrp * 4 + r;
                        int col = w * 64 + ni * 16 + lrow;
                        float val = selu_f(acc[mi][ni][r] + bc[ni]);
                        *(short*)&lds[row * 512 + ((col * 2) ^ ((row & 7) << 4))] = f2h(val);
                    }
            // next loop iteration's first barrier makes these visible
        } else {
            // ---- epilogue: 2 rounds of 32 rows via B region (32KB) ----
            unsigned char* EP = lds + 32768;
#pragma unroll
            for (int cc = 0; cc < 2; ++cc) {
                if (cc) __syncthreads();
#pragma unroll
                for (int m2 = 0; m2 < 2; ++m2) {
                    int mi = cc * 2 + m2;
#pragma unroll
                    for (int ni = 0; ni < 4; ++ni)
#pragma unroll
                        for (int r = 0; r < 4; ++r) {
                            int lr = m2 * 16 + lgrp * 4 + r;       // 0..31
                            int cg = w * 64 + ni * 16 + lrow;
                            float val = selu_f(acc[mi][ni][r] + bc[ni]);
                            *(float*)&EP[lr * 1024 + cg * 4] = val;
                            int e = base + cc * 32 + lr;
                            atomicAdd(agg + (size_t)dstI[e] * HF + cg, val);
                        }
                }
                __syncthreads();
#pragma unroll
                for (int i = 0; i < 8; ++i) {
                    int f = t + i * 256;                  // 2048 x 16B = 32 rows x 64
                    int row = f >> 6, ch = f & 63;
                    f32x4 v = *(const f32x4*)&EP[row * 1024 + ch * 16];
                    *(f32x4*)(hB + (size_t)(base + cc * 32 + row) * 1024 + ch * 16) = v;
                }
            }
        }
    }
}

extern "C" void kernel_launch(void* const* d_in, const int* in_sizes, int n_in,
                              void* d_out, int out_size, void* d_ws, size_t ws_size,
                              hipStream_t stream) {
    const float* x     = (const float*)d_in[0];
    const int*   ei    = (const int*)d_in[1];
    const float* W0    = (const float*)d_in[2];
    const float* b0    = (const float*)d_in[3];
    const float* g0    = (const float*)d_in[4];
    const float* beta0 = (const float*)d_in[5];
    const float* m0    = (const float*)d_in[6];
    const float* v0    = (const float*)d_in[7];
    const float* Ws    = (const float*)d_in[8];
    const float* bs    = (const float*)d_in[9];
    const float* gs    = (const float*)d_in[10];
    const float* betas = (const float*)d_in[11];
    const float* ms    = (const float*)d_in[12];
    const float* vs    = (const float*)d_in[13];

    const int Nn = in_sizes[0] / IN_F;   // 20000
    const int E  = in_sizes[1] / 2;      // 320000

    float* agg  = (float*)d_out;
    float* hptr = agg + (size_t)Nn * HF;   // final h region of d_out

    // ws: Wf (384KB fp16, staged layout) | biasArr (3KB) | cnt (80KB)
    unsigned short* Wf = (unsigned short*)d_ws;
    float* biasArr = (float*)((char*)d_ws + 3 * HF * HF * sizeof(unsigned short));
    int* cnt = (int*)((char*)d_ws + 3 * HF * HF * sizeof(unsigned short) + 3 * HF * sizeof(float));

    const int* srcI = ei;        // edge_index[0]
    const int* dstI = ei + E;    // edge_index[1]

    prep_kernel<<<3 * HF, HF, 0, stream>>>(W0, b0, g0, beta0, m0, v0,
                                           Ws, bs, gs, betas, ms, vs, Wf, biasArr);
    hipMemsetAsync(cnt, 0, (size_t)Nn * sizeof(int), stream);
    hipMemsetAsync(agg, 0, (size_t)Nn * HF * sizeof(float), stream);
    count_kernel<<<(E + 255) / 256, 256, 0, stream>>>(dstI, cnt, E);

    fused_kernel<<<E / 64, 256, 0, stream>>>(x, dstI, srcI,
                                             (const unsigned char*)Wf, biasArr,
                                             (unsigned char*)hptr, agg);

    finalize_kernel<<<Nn, HF, 0, stream>>>(agg, cnt);
}

// Round 11
// 394.000 us; speedup vs baseline: 3.1845x; 1.2322x over previous
//
#include <hip/hip_runtime.h>
#include <hip/hip_bf16.h>

#define IN_F 128
#define HF 256
#define BN_EPS 1e-5f
#define SELU_SCALE 1.0507009873554805f
#define SELU_ALPHA 1.6732632423543772f

typedef __attribute__((ext_vector_type(8))) _Float16 half8;
typedef __attribute__((ext_vector_type(2))) unsigned int u32x2;
typedef __attribute__((ext_vector_type(4))) float f32x4;

__device__ __forceinline__ short f2h(float f) {
    _Float16 h = (_Float16)f;               // RTNE fp32->fp16
    return __builtin_bit_cast(short, h);
}

// fast SELU: native v_exp_f32; exp result discarded by select when x>0
__device__ __forceinline__ float selu_f(float x) {
    const float SA = SELU_SCALE * SELU_ALPHA;
    float e = __expf(x);
    return x > 0.f ? SELU_SCALE * x : SA * e - SA;
}

// pack 2 fp32 -> 2 fp16 (RTZ), one instruction
__device__ __forceinline__ unsigned int pk2h(float a, float b) {
    return __builtin_bit_cast(unsigned int, __builtin_amdgcn_cvt_pkrtz(a, b));
}

// async global->LDS, 16B/lane; LDS dest MUST be wave-uniform (lane*16 implicit)
__device__ __forceinline__ void gld_lds16(const void* g, void* l) {
    __builtin_amdgcn_global_load_lds(
        (const __attribute__((address_space(1))) unsigned int*)g,
        (__attribute__((address_space(3))) unsigned int*)l, 16, 0, 0);
}

// Fold BN into weights. Layout matches fused kernel's per-step B staging:
// Wf[layer][kk(4)][kc(8)][n(256)][j(8)] fp16, k = kk*64 + kc*8 + j.
__global__ void prep_kernel(const float* __restrict__ W0, const float* __restrict__ b0,
                            const float* __restrict__ g0, const float* __restrict__ beta0,
                            const float* __restrict__ m0, const float* __restrict__ v0,
                            const float* __restrict__ Ws, const float* __restrict__ bs,
                            const float* __restrict__ gs, const float* __restrict__ betas,
                            const float* __restrict__ ms, const float* __restrict__ vs,
                            unsigned short* __restrict__ Wf, float* __restrict__ biasArr) {
    int b = blockIdx.x;
    int layer = b >> 8;
    int n = b & 255;
    int k = threadIdx.x;
    const float *W, *bb, *g, *be, *m, *v;
    if (layer == 0) { W = W0; bb = b0; g = g0; be = beta0; m = m0; v = v0; }
    else {
        int i = layer - 1;
        W = Ws + (size_t)i * HF * HF; bb = bs + i * HF; g = gs + i * HF;
        be = betas + i * HF; m = ms + i * HF; v = vs + i * HF;
    }
    float s = g[n] * rsqrtf(v[n] + BN_EPS);
    int kk = k >> 6, kc = (k >> 3) & 7, j = k & 7;
    Wf[((((size_t)layer * 4 + kk) * 8 + kc) * 256 + n) * 8 + j] =
        (unsigned short)f2h(W[n * HF + k] * s);
    if (k == 0) biasArr[layer * HF + n] = (bb[n] - m[n]) * s + be[n];
}

__global__ void count_kernel(const int* __restrict__ dstI, int* __restrict__ cnt, int E) {
    int i = blockIdx.x * 256 + threadIdx.x;
    if (i < E) atomicAdd(cnt + dstI[i], 1);
}

__global__ void finalize_kernel(float* __restrict__ agg, const int* __restrict__ cnt) {
    int n = blockIdx.x;
    float c = fmaxf((float)cnt[n], 1.f);
    agg[(size_t)n * HF + threadIdx.x] = agg[(size_t)n * HF + threadIdx.x] / c;
}

// Fused 3-layer edge MLP. Block = 64 edges x all 256 cols; 256 thr = 4 waves,
// each wave 64 rows x 64 cols (4x4 frags of mfma_f32_16x16x32_f16).
// A_act: 64 rows x 512B fp16 @0, XOR-swizzled (byte ^ ((row&7)<<4)), resident
//   across layers. B: 32KB @32768, [kc][n][16B], staged per BK=64 step; the
//   stage for step k+1 is issued AFTER the post-read barrier and overlaps the
//   MFMA cluster. Layers 1-2 use SWAPPED mfma operands (lane&15=edge,
//   reg-dim=col) so the handoff packs 4 consecutive cols per lane ->
//   cvt_pkrtz + ds_write_b64. Layer 3 unswapped -> 64B-coalesced atomics.
__global__ __launch_bounds__(256, 2)
void fused_kernel(const float* __restrict__ x,
                  const int* __restrict__ dstI, const int* __restrict__ srcI,
                  const unsigned char* __restrict__ Wfb,
                  const float* __restrict__ biasArr,
                  unsigned char* __restrict__ hB, float* __restrict__ agg) {
    __shared__ __align__(16) unsigned char lds[65536];

    const int base = blockIdx.x * 64;
    const int t = threadIdx.x;
    const int lane = t & 63;
    const int w = t >> 6;           // 0..3 : 64-col slab
    const int lrow = lane & 15;
    const int lgrp = lane >> 4;

    // stage B(L,kk): 32KB, 8 wave-uniform gld_lds rounds
    auto stageB = [&](int L, int kk) {
        const unsigned char* src = Wfb + ((size_t)(L * 4 + kk) << 15);
        unsigned char* dstBase = lds + 32768 + w * 1024;
#pragma unroll
        for (int i = 0; i < 8; ++i)
            gld_lds16(src + (i * 256 + t) * 16, dstBase + i * 4096);
    };

    stageB(0, 0);   // overlap with gather below

    // ---- layer-1 A fill: gather x fp32 (L2/L3-hot), pack, swizzled write ----
    {
        int r = t >> 2, q = t & 3;                 // row, col-quarter
        int idx = (q < 2 ? dstI : srcI)[base + r];
        const float* xr = x + (size_t)idx * IN_F + (q & 1) * 64;
        int swz = (r & 7) << 4;
#pragma unroll
        for (int u = 0; u < 16; ++u) {
            f32x4 v = *(const f32x4*)(xr + u * 4);
            u32x2 hv = {pk2h(v[0], v[1]), pk2h(v[2], v[3])};
            *(u32x2*)&lds[r * 512 + ((q * 128 + u * 8) ^ swz)] = hv;
        }
    }

    f32x4 acc[4][4];
    const f32x4 zero = {0.f, 0.f, 0.f, 0.f};

#pragma unroll
    for (int L = 0; L < 3; ++L) {
#pragma unroll
        for (int mi = 0; mi < 4; ++mi)
#pragma unroll
            for (int ni = 0; ni < 4; ++ni) acc[mi][ni] = zero;

#pragma unroll
        for (int kk = 0; kk < 4; ++kk) {
            __syncthreads();   // B(kk) staged + A_act writes visible

            half8 af[4][2], bf[4][2];
#pragma unroll
            for (int mi = 0; mi < 4; ++mi)
#pragma unroll
                for (int kI = 0; kI < 2; ++kI) {
                    int row = mi * 16 + lrow;
                    af[mi][kI] = *(const half8*)&lds[row * 512 +
                        ((kk * 128 + kI * 64 + lgrp * 16) ^ ((row & 7) << 4))];
                }
#pragma unroll
            for (int ni = 0; ni < 4; ++ni)
#pragma unroll
                for (int kI = 0; kI < 2; ++kI)
                    bf[ni][kI] = *(const half8*)&lds[32768 + (kI * 4 + lgrp) * 4096 +
                                                     (w * 64 + ni * 16 + lrow) * 16];
            __syncthreads();   // all waves have their frags -> B buffer free

            // stage next B under the MFMA cluster
            if (kk < 3) stageB(L, kk + 1);
            else if (L < 2) stageB(L + 1, 0);

            if (L < 2) {
#pragma unroll
                for (int kI = 0; kI < 2; ++kI)
#pragma unroll
                    for (int mi = 0; mi < 4; ++mi)
#pragma unroll
                        for (int ni = 0; ni < 4; ++ni)
                            acc[mi][ni] = __builtin_amdgcn_mfma_f32_16x16x32_f16(
                                bf[ni][kI], af[mi][kI], acc[mi][ni], 0, 0, 0);
            } else {
#pragma unroll
                for (int kI = 0; kI < 2; ++kI)
#pragma unroll
                    for (int mi = 0; mi < 4; ++mi)
#pragma unroll
                        for (int ni = 0; ni < 4; ++ni)
                            acc[mi][ni] = __builtin_amdgcn_mfma_f32_16x16x32_f16(
                                af[mi][kI], bf[ni][kI], acc[mi][ni], 0, 0, 0);
            }
        }

        if (L < 2) {
            // ---- handoff (swapped layout): lane&15 = edge, reg-dim = col ----
            // lane holds cols ni*16 + lgrp*4 + {0..3} of edge mi*16 + lrow:
            // selu -> pkrtz pairs -> one b64 swizzled write per frag.
#pragma unroll
            for (int ni = 0; ni < 4; ++ni) {
                f32x4 bv = *(const f32x4*)(biasArr + L * HF + w * 64 + ni * 16 + lgrp * 4);
#pragma unroll
                for (int mi = 0; mi < 4; ++mi) {
                    int row = mi * 16 + lrow;
                    float v0 = selu_f(acc[mi][ni][0] + bv[0]);
                    float v1 = selu_f(acc[mi][ni][1] + bv[1]);
                    float v2 = selu_f(acc[mi][ni][2] + bv[2]);
                    float v3 = selu_f(acc[mi][ni][3] + bv[3]);
                    u32x2 d = {pk2h(v0, v1), pk2h(v2, v3)};
                    *(u32x2*)&lds[row * 512 +
                        ((w * 128 + ni * 32 + lgrp * 8) ^ ((row & 7) << 4))] = d;
                }
            }
            // next kk loop's first barrier publishes these
        } else {
            // ---- epilogue (unswapped): coalesced atomics + full-line h ----
            float bc[4];
#pragma unroll
            for (int ni = 0; ni < 4; ++ni) bc[ni] = biasArr[2 * HF + w * 64 + ni * 16 + lrow];
            unsigned char* EP = lds + 32768;
#pragma unroll
            for (int cc = 0; cc < 2; ++cc) {
                if (cc) __syncthreads();
#pragma unroll
                for (int m2 = 0; m2 < 2; ++m2) {
                    int mi = cc * 2 + m2;
#pragma unroll
                    for (int ni = 0; ni < 4; ++ni)
#pragma unroll
                        for (int r = 0; r < 4; ++r) {
                            int lr = m2 * 16 + lgrp * 4 + r;       // 0..31
                            int cg = w * 64 + ni * 16 + lrow;
                            float val = selu_f(acc[mi][ni][r] + bc[ni]);
                            *(float*)&EP[lr * 1024 + ((cg * 4) ^ ((lr & 7) << 4))] = val;
                            int e = base + cc * 32 + lr;
                            atomicAdd(agg + (size_t)dstI[e] * HF + cg, val);
                        }
                }
                __syncthreads();
#pragma unroll
                for (int i = 0; i < 8; ++i) {
                    int f = t + i * 256;                  // 2048 x 16B = 32 rows x 64
                    int row = f >> 6, ch = f & 63;
                    f32x4 v = *(const f32x4*)&EP[row * 1024 + ((ch * 16) ^ ((row & 7) << 4))];
                    *(f32x4*)(hB + (size_t)(base + cc * 32 + row) * 1024 + ch * 16) = v;
                }
            }
        }
    }
}

extern "C" void kernel_launch(void* const* d_in, const int* in_sizes, int n_in,
                              void* d_out, int out_size, void* d_ws, size_t ws_size,
                              hipStream_t stream) {
    const float* x     = (const float*)d_in[0];
    const int*   ei    = (const int*)d_in[1];
    const float* W0    = (const float*)d_in[2];
    const float* b0    = (const float*)d_in[3];
    const float* g0    = (const float*)d_in[4];
    const float* beta0 = (const float*)d_in[5];
    const float* m0    = (const float*)d_in[6];
    const float* v0    = (const float*)d_in[7];
    const float* Ws    = (const float*)d_in[8];
    const float* bs    = (const float*)d_in[9];
    const float* gs    = (const float*)d_in[10];
    const float* betas = (const float*)d_in[11];
    const float* ms    = (const float*)d_in[12];
    const float* vs    = (const float*)d_in[13];

    const int Nn = in_sizes[0] / IN_F;   // 20000
    const int E  = in_sizes[1] / 2;      // 320000

    float* agg  = (float*)d_out;
    float* hptr = agg + (size_t)Nn * HF;   // final h region of d_out

    // ws: Wf (384KB fp16, staged layout) | biasArr (3KB) | cnt (80KB)
    unsigned short* Wf = (unsigned short*)d_ws;
    float* biasArr = (float*)((char*)d_ws + 3 * HF * HF * sizeof(unsigned short));
    int* cnt = (int*)((char*)d_ws + 3 * HF * HF * sizeof(unsigned short) + 3 * HF * sizeof(float));

    const int* srcI = ei;        // edge_index[0]
    const int* dstI = ei + E;    // edge_index[1]

    prep_kernel<<<3 * HF, HF, 0, stream>>>(W0, b0, g0, beta0, m0, v0,
                                           Ws, bs, gs, betas, ms, vs, Wf, biasArr);
    hipMemsetAsync(cnt, 0, (size_t)Nn * sizeof(int), stream);
    hipMemsetAsync(agg, 0, (size_t)Nn * HF * sizeof(float), stream);
    count_kernel<<<(E + 255) / 256, 256, 0, stream>>>(dstI, cnt, E);

    fused_kernel<<<E / 64, 256, 0, stream>>>(x, dstI, srcI,
                                             (const unsigned char*)Wf, biasArr,
                                             (unsigned char*)hptr, agg);

    finalize_kernel<<<Nn, HF, 0, stream>>>(agg, cnt);
}